// Round 1
// baseline (45.728 us; speedup 1.0000x reference)
//
#include <hip/hip_runtime.h>

#define BS 128
#define KJ 17
#define HW 4096
#define CHUNKS 4
#define NBLK1 (BS * CHUNKS)      // 512
#define CHUNK_SZ (HW / CHUNKS)   // 1024
#define ITERS (CHUNK_SZ / 256)   // 4
#define NBK (BS * KJ)            // 2176
#define KSEL 1088                // int(2176 * (1 - 0.5))

// ws float offsets
#define PL_OFF 0
#define S1_OFF (NBLK1 * KJ)          // 8704
#define S2_OFF (2 * NBLK1 * KJ)      // 17408
#define LW_OFF (3 * NBLK1 * KJ)      // 26112
#define SA_OFF (LW_OFF + NBK)
#define SB_OFF (SA_OFF + NBK)
#define THR_OFF (SB_OFF + NBK)       // +2 floats

// ---------------- K1: big streaming reduce ----------------
// grid 512 (= b*4 + chunk), block 256. Per thread: spatial position s,
// loop over 17 joints; accumulate per-k SSQ(pred - tmean) and per-k
// max over s of softmax_k(v)[k].
__global__ __launch_bounds__(256) void k1_reduce(const float* __restrict__ preds,
                                                 const float* __restrict__ targets,
                                                 float* __restrict__ ws) {
    const int bid = blockIdx.x;
    const int b = bid >> 2;
    const int c = bid & 3;
    const int tid = threadIdx.x;

    const float* pb  = preds   + (size_t)b * KJ * HW;
    const float* t0b = targets + (size_t)b * KJ * HW;
    const float* t1b = targets + (size_t)(BS + b) * KJ * HW;

    float lacc[KJ], sc1[KJ], sc2[KJ];
#pragma unroll
    for (int k = 0; k < KJ; ++k) { lacc[k] = 0.f; sc1[k] = 0.f; sc2[k] = 0.f; }

    for (int it = 0; it < ITERS; ++it) {
        const int s = c * CHUNK_SZ + it * 256 + tid;
        float p[KJ], t[KJ];
        float m1 = -1e30f, m2 = -1e30f;
#pragma unroll
        for (int k = 0; k < KJ; ++k) {
            float pv = pb[k * HW + s];
            float ta = t0b[k * HW + s];
            float tb = t1b[k * HW + s];
            float tv = 0.5f * (ta + tb);
            p[k] = pv; t[k] = tv;
            float d = pv - tv;
            lacc[k] += d * d;
            m1 = fmaxf(m1, pv);
            m2 = fmaxf(m2, tv);
        }
        float sum1 = 0.f, sum2 = 0.f;
#pragma unroll
        for (int k = 0; k < KJ; ++k) {
            p[k] = __expf(p[k] - m1); sum1 += p[k];
            t[k] = __expf(t[k] - m2); sum2 += t[k];
        }
        const float i1 = 1.0f / sum1;
        const float i2 = 1.0f / sum2;
#pragma unroll
        for (int k = 0; k < KJ; ++k) {
            sc1[k] = fmaxf(sc1[k], p[k] * i1);
            sc2[k] = fmaxf(sc2[k], t[k] * i2);
        }
    }

    // ---- block reduce: LDS tree, 3 phases reusing one buffer ----
    __shared__ float buf[KJ][256];

    // phase 1: loss sum
#pragma unroll
    for (int k = 0; k < KJ; ++k) buf[k][tid] = lacc[k];
    __syncthreads();
    for (int st = 128; st > 0; st >>= 1) {
        if (tid < st) {
#pragma unroll
            for (int k = 0; k < KJ; ++k) buf[k][tid] += buf[k][tid + st];
        }
        __syncthreads();
    }
    if (tid < KJ) ws[PL_OFF + bid * KJ + tid] = buf[tid][0];
    __syncthreads();

    // phase 2: score1 max
#pragma unroll
    for (int k = 0; k < KJ; ++k) buf[k][tid] = sc1[k];
    __syncthreads();
    for (int st = 128; st > 0; st >>= 1) {
        if (tid < st) {
#pragma unroll
            for (int k = 0; k < KJ; ++k) buf[k][tid] = fmaxf(buf[k][tid], buf[k][tid + st]);
        }
        __syncthreads();
    }
    if (tid < KJ) ws[S1_OFF + bid * KJ + tid] = buf[tid][0];
    __syncthreads();

    // phase 3: score2 max
#pragma unroll
    for (int k = 0; k < KJ; ++k) buf[k][tid] = sc2[k];
    __syncthreads();
    for (int st = 128; st > 0; st >>= 1) {
        if (tid < st) {
#pragma unroll
            for (int k = 0; k < KJ; ++k) buf[k][tid] = fmaxf(buf[k][tid], buf[k][tid + st]);
        }
        __syncthreads();
    }
    if (tid < KJ) ws[S2_OFF + bid * KJ + tid] = buf[tid][0];
}

// ---------------- K2: fold chunk partials ----------------
__global__ __launch_bounds__(256) void k2_fold(float* __restrict__ ws,
                                               const float* __restrict__ sw) {
    const int e = blockIdx.x * 256 + threadIdx.x;
    if (e >= NBK) return;
    const int b = e / KJ;
    const int k = e - b * KJ;
    float L = 0.f, S1 = 0.f, S2 = 0.f;
#pragma unroll
    for (int c = 0; c < CHUNKS; ++c) {
        const int idx = (b * CHUNKS + c) * KJ + k;
        L += ws[PL_OFF + idx];
        S1 = fmaxf(S1, ws[S1_OFF + idx]);
        S2 = fmaxf(S2, ws[S2_OFF + idx]);
    }
    ws[LW_OFF + e] = L * (1.0f / HW) * sw[b];
    ws[SA_OFF + e] = S1;
    ws[SB_OFF + e] = S2;
}

// ---------------- K3: order statistic (index KSEL of ascending sort) ----
// One wave per candidate element, 2 arrays x 2176 candidates = 4352 waves.
__global__ __launch_bounds__(256) void k3_select(float* __restrict__ ws) {
    const int w = blockIdx.x * 4 + (threadIdx.x >> 6);  // 0..4351
    const int lane = threadIdx.x & 63;
    const int arr = (w >= NBK) ? 1 : 0;
    const int cand = w - arr * NBK;
    const float* sc = ws + (arr ? SB_OFF : SA_OFF);
    const float e = sc[cand];
    int clt = 0, cle = 0;
    for (int j = lane; j < NBK; j += 64) {
        float x = sc[j];
        clt += (x < e) ? 1 : 0;
        cle += (x <= e) ? 1 : 0;
    }
#pragma unroll
    for (int off = 32; off > 0; off >>= 1) {
        clt += __shfl_xor(clt, off, 64);
        cle += __shfl_xor(cle, off, 64);
    }
    if (lane == 0 && clt <= KSEL && KSEL < cle) {
        ws[THR_OFF + arr] = e;  // unique value; benign same-value race
    }
}

// ---------------- K4: finalize all 22 outputs ----------------
__global__ __launch_bounds__(256) void k4_final(const float* __restrict__ ws,
                                                const float* __restrict__ sw,
                                                float* __restrict__ out) {
    const int tid = threadIdx.x;
    const float thrA = ws[THR_OFF + 0];
    const float thrB = ws[THR_OFF + 1];

    float comb = 0.f, np = 0.f, ns = 0.f;
    for (int e = tid; e < NBK; e += 256) {
        const float L  = ws[LW_OFF + e];
        const float s1 = ws[SA_OFF + e];
        const float s2 = ws[SB_OFF + e];
        const float m = (s1 >= thrA && s2 >= thrB) ? 1.f : 0.f;
        comb += L * m;
        np += (L > 0.f) ? 1.f : 0.f;
        ns += m;
    }
#pragma unroll
    for (int off = 32; off > 0; off >>= 1) {
        comb += __shfl_xor(comb, off, 64);
        np   += __shfl_xor(np, off, 64);
        ns   += __shfl_xor(ns, off, 64);
    }
    __shared__ float wr[4][3];
    const int wid = tid >> 6, lane = tid & 63;
    if (lane == 0) { wr[wid][0] = comb; wr[wid][1] = np; wr[wid][2] = ns; }
    __syncthreads();
    if (tid == 0) {
        float C = 0.f, NP = 0.f, NS = 0.f;
#pragma unroll
        for (int i = 0; i < 4; ++i) { C += wr[i][0]; NP += wr[i][1]; NS += wr[i][2]; }
        out[0] = C;
        out[1] = NP;
        out[2] = NS;
        out[20] = thrA;
        out[21] = thrB;
    }
    // joint_score_mean: deterministic serial sum over b for each k
    if (tid < KJ) {
        float a1 = 0.f, a2 = 0.f, cnt = 0.f;
        for (int b = 0; b < BS; ++b) {
            const float wf = (sw[b] > 0.f) ? 1.f : 0.f;
            cnt += wf;
            a1 += ws[SA_OFF + b * KJ + tid] * wf;
            a2 += ws[SB_OFF + b * KJ + tid] * wf;
        }
        out[3 + tid] = 0.5f * (a1 + a2) / cnt;
    }
}

extern "C" void kernel_launch(void* const* d_in, const int* in_sizes, int n_in,
                              void* d_out, int out_size, void* d_ws, size_t ws_size,
                              hipStream_t stream) {
    const float* preds   = (const float*)d_in[0];
    const float* targets = (const float*)d_in[1];
    const float* sw      = (const float*)d_in[2];
    float* out = (float*)d_out;
    float* ws  = (float*)d_ws;

    hipLaunchKernelGGL(k1_reduce, dim3(NBLK1), dim3(256), 0, stream, preds, targets, ws);
    hipLaunchKernelGGL(k2_fold, dim3((NBK + 255) / 256), dim3(256), 0, stream, ws, sw);
    hipLaunchKernelGGL(k3_select, dim3((2 * NBK) / 4), dim3(256), 0, stream, ws);
    hipLaunchKernelGGL(k4_final, dim3(1), dim3(256), 0, stream, ws, sw, out);
}

// Round 2
// 41.784 us; speedup vs baseline: 1.0944x; 1.0944x over previous
//
#include <hip/hip_runtime.h>

#define BS 128
#define KJ 17
#define HW 4096
#define CHUNKS 16
#define NBLK1 (BS * CHUNKS)      // 2048 blocks, 256 threads: 1 position/thread
#define NBK (BS * KJ)            // 2176
#define KSEL 1088                // int(2176 * (1 - 0.5))

// ws float offsets
#define PL_OFF 0
#define S1_OFF (NBLK1 * KJ)          // 34816
#define S2_OFF (2 * NBLK1 * KJ)      // 69632
#define LW_OFF (3 * NBLK1 * KJ)      // 104448
#define SA_OFF (LW_OFF + NBK)
#define SB_OFF (SA_OFF + NBK)
#define THR_OFF (SB_OFF + NBK)       // +2 floats

// ---------------- K1: big streaming reduce ----------------
// grid 2048 (= b*16 + c), block 256, one spatial position per thread.
// Per thread: all 17 joints; per-position softmax for preds and target-mean;
// block-reduce loss-sum and score-max via two-stage LDS reduce.
__global__ __launch_bounds__(256) void k1_reduce(const float* __restrict__ preds,
                                                 const float* __restrict__ targets,
                                                 float* __restrict__ ws) {
    __shared__ float buf[256][18];   // [tid][k], pad 18 floats
    __shared__ float buf2[KJ][8];    // per-segment partials

    const int bid = blockIdx.x;
    const int b = bid >> 4;
    const int c = bid & 15;
    const int tid = threadIdx.x;
    const int s = (c << 8) | tid;

    const float* pb  = preds   + (size_t)b * KJ * HW + s;
    const float* t0b = targets + (size_t)b * KJ * HW + s;
    const float* t1b = targets + (size_t)(BS + b) * KJ * HW + s;

    float p[KJ], t[KJ];
    float m1 = -1e30f, m2 = -1e30f;
#pragma unroll
    for (int k = 0; k < KJ; ++k) {
        float pv = pb[k * HW];
        float ta = t0b[k * HW];
        float tb = t1b[k * HW];
        float tv = 0.5f * (ta + tb);
        p[k] = pv; t[k] = tv;
        m1 = fmaxf(m1, pv);
        m2 = fmaxf(m2, tv);
    }

    // ---- phase 1: per-(b,k) loss sum over this block's 256 positions ----
#pragma unroll
    for (int k = 0; k < KJ; ++k) { float d = p[k] - t[k]; buf[tid][k] = d * d; }
    __syncthreads();
    if (tid < KJ * 8) {
        const int k = tid >> 3, seg = tid & 7;
        float r = 0.f;
#pragma unroll
        for (int i = 0; i < 32; ++i) {
            const int idx = (i + seg * 4) & 31;   // phase-rotate: 2-way banks max
            r += buf[(seg << 5) + idx][k];
        }
        buf2[k][seg] = r;
    }
    __syncthreads();
    if (tid < KJ) {
        float r = 0.f;
#pragma unroll
        for (int i = 0; i < 8; ++i) r += buf2[tid][i];
        ws[PL_OFF + bid * KJ + tid] = r;
    }

    // ---- phase 2: score1 = max over positions of softmax(preds) ----
    float sum1 = 0.f;
#pragma unroll
    for (int k = 0; k < KJ; ++k) { p[k] = __expf(p[k] - m1); sum1 += p[k]; }
    const float i1 = 1.0f / sum1;
#pragma unroll
    for (int k = 0; k < KJ; ++k) buf[tid][k] = p[k] * i1;
    __syncthreads();
    if (tid < KJ * 8) {
        const int k = tid >> 3, seg = tid & 7;
        float r = 0.f;                            // softmax > 0
#pragma unroll
        for (int i = 0; i < 32; ++i) {
            const int idx = (i + seg * 4) & 31;
            r = fmaxf(r, buf[(seg << 5) + idx][k]);
        }
        buf2[k][seg] = r;
    }
    __syncthreads();
    if (tid < KJ) {
        float r = 0.f;
#pragma unroll
        for (int i = 0; i < 8; ++i) r = fmaxf(r, buf2[tid][i]);
        ws[S1_OFF + bid * KJ + tid] = r;
    }

    // ---- phase 3: score2 = max over positions of softmax(target mean) ----
    float sum2 = 0.f;
#pragma unroll
    for (int k = 0; k < KJ; ++k) { t[k] = __expf(t[k] - m2); sum2 += t[k]; }
    const float i2 = 1.0f / sum2;
#pragma unroll
    for (int k = 0; k < KJ; ++k) buf[tid][k] = t[k] * i2;
    __syncthreads();
    if (tid < KJ * 8) {
        const int k = tid >> 3, seg = tid & 7;
        float r = 0.f;
#pragma unroll
        for (int i = 0; i < 32; ++i) {
            const int idx = (i + seg * 4) & 31;
            r = fmaxf(r, buf[(seg << 5) + idx][k]);
        }
        buf2[k][seg] = r;
    }
    __syncthreads();
    if (tid < KJ) {
        float r = 0.f;
#pragma unroll
        for (int i = 0; i < 8; ++i) r = fmaxf(r, buf2[tid][i]);
        ws[S2_OFF + bid * KJ + tid] = r;
    }
}

// ---------------- K2: fold chunk partials ----------------
__global__ __launch_bounds__(256) void k2_fold(float* __restrict__ ws,
                                               const float* __restrict__ sw) {
    const int e = blockIdx.x * 256 + threadIdx.x;
    if (e >= NBK) return;
    const int b = e / KJ;
    const int k = e - b * KJ;
    float L = 0.f, S1 = 0.f, S2 = 0.f;
#pragma unroll
    for (int c = 0; c < CHUNKS; ++c) {
        const int idx = (b * CHUNKS + c) * KJ + k;
        L += ws[PL_OFF + idx];
        S1 = fmaxf(S1, ws[S1_OFF + idx]);
        S2 = fmaxf(S2, ws[S2_OFF + idx]);
    }
    ws[LW_OFF + e] = L * (1.0f / HW) * sw[b];
    ws[SA_OFF + e] = S1;
    ws[SB_OFF + e] = S2;
}

// ---------------- K3: order statistic (index KSEL of ascending sort) ----
// One wave per candidate element, 2 arrays x 2176 candidates = 4352 waves.
__global__ __launch_bounds__(256) void k3_select(float* __restrict__ ws) {
    const int w = blockIdx.x * 4 + (threadIdx.x >> 6);  // 0..4351
    const int lane = threadIdx.x & 63;
    const int arr = (w >= NBK) ? 1 : 0;
    const int cand = w - arr * NBK;
    const float* sc = ws + (arr ? SB_OFF : SA_OFF);
    const float e = sc[cand];
    int clt = 0, cle = 0;
    for (int j = lane; j < NBK; j += 64) {
        float x = sc[j];
        clt += (x < e) ? 1 : 0;
        cle += (x <= e) ? 1 : 0;
    }
#pragma unroll
    for (int off = 32; off > 0; off >>= 1) {
        clt += __shfl_xor(clt, off, 64);
        cle += __shfl_xor(cle, off, 64);
    }
    if (lane == 0 && clt <= KSEL && KSEL < cle) {
        ws[THR_OFF + arr] = e;  // unique value; benign same-value race
    }
}

// ---------------- K4: finalize all 22 outputs ----------------
__global__ __launch_bounds__(256) void k4_final(const float* __restrict__ ws,
                                                const float* __restrict__ sw,
                                                float* __restrict__ out) {
    const int tid = threadIdx.x;
    const float thrA = ws[THR_OFF + 0];
    const float thrB = ws[THR_OFF + 1];

    float comb = 0.f, np = 0.f, ns = 0.f;
    for (int e = tid; e < NBK; e += 256) {
        const float L  = ws[LW_OFF + e];
        const float s1 = ws[SA_OFF + e];
        const float s2 = ws[SB_OFF + e];
        const float m = (s1 >= thrA && s2 >= thrB) ? 1.f : 0.f;
        comb += L * m;
        np += (L > 0.f) ? 1.f : 0.f;
        ns += m;
    }
#pragma unroll
    for (int off = 32; off > 0; off >>= 1) {
        comb += __shfl_xor(comb, off, 64);
        np   += __shfl_xor(np, off, 64);
        ns   += __shfl_xor(ns, off, 64);
    }
    __shared__ float wr[4][3];
    const int wid = tid >> 6, lane = tid & 63;
    if (lane == 0) { wr[wid][0] = comb; wr[wid][1] = np; wr[wid][2] = ns; }
    __syncthreads();
    if (tid == 0) {
        float C = 0.f, NP = 0.f, NS = 0.f;
#pragma unroll
        for (int i = 0; i < 4; ++i) { C += wr[i][0]; NP += wr[i][1]; NS += wr[i][2]; }
        out[0] = C;
        out[1] = NP;
        out[2] = NS;
        out[20] = thrA;
        out[21] = thrB;
    }
    // joint_score_mean: deterministic serial sum over b for each k
    if (tid < KJ) {
        float a1 = 0.f, a2 = 0.f, cnt = 0.f;
        for (int b = 0; b < BS; ++b) {
            const float wf = (sw[b] > 0.f) ? 1.f : 0.f;
            cnt += wf;
            a1 += ws[SA_OFF + b * KJ + tid] * wf;
            a2 += ws[SB_OFF + b * KJ + tid] * wf;
        }
        out[3 + tid] = 0.5f * (a1 + a2) / cnt;
    }
}

extern "C" void kernel_launch(void* const* d_in, const int* in_sizes, int n_in,
                              void* d_out, int out_size, void* d_ws, size_t ws_size,
                              hipStream_t stream) {
    const float* preds   = (const float*)d_in[0];
    const float* targets = (const float*)d_in[1];
    const float* sw      = (const float*)d_in[2];
    float* out = (float*)d_out;
    float* ws  = (float*)d_ws;

    hipLaunchKernelGGL(k1_reduce, dim3(NBLK1), dim3(256), 0, stream, preds, targets, ws);
    hipLaunchKernelGGL(k2_fold, dim3((NBK + 255) / 256), dim3(256), 0, stream, ws, sw);
    hipLaunchKernelGGL(k3_select, dim3((2 * NBK) / 4), dim3(256), 0, stream, ws);
    hipLaunchKernelGGL(k4_final, dim3(1), dim3(256), 0, stream, ws, sw, out);
}